// Round 5
// baseline (94.687 us; speedup 1.0000x reference)
//
#include <hip/hip_runtime.h>

// Closed form of the reference QP:
//   z_unc = (x*x, 1);  z_act = (-x, 1)
//   feasible = (-x^2 <= x)  -> z = feasible ? z_unc : z_act
// Output [B,2] row-major float32: interleaved (z1, 1.0) pairs.
//
// Thread j reads x[2j:2j+2] as float2 (8B/lane, lane-contiguous) and writes
// out[4j:4j+4] as one float4 (16B/lane, lane-contiguous) -- no strided
// stores. Grid-stride at 2048 blocks; nontemporal load/store (read-once /
// write-once streaming).

typedef float f4v __attribute__((ext_vector_type(4)));
typedef float f2v __attribute__((ext_vector_type(2)));

__global__ __launch_bounds__(256) void qp_kernel(const f2v* __restrict__ x2,
                                                 f4v* __restrict__ out4,
                                                 int n2 /* = B/2 */) {
    int stride = gridDim.x * blockDim.x;
    for (int i = blockIdx.x * blockDim.x + threadIdx.x; i < n2; i += stride) {
        f2v xv = __builtin_nontemporal_load(&x2[i]);
        float a = xv.x, b = xv.y;
        float sa = a * a, sb = b * b;
        // feasible: -x^2 <= x (NaN -> false -> z_act, matching jnp.where)
        float za = (-sa <= a) ? sa : -a;
        float zb = (-sb <= b) ? sb : -b;
        f4v o = {za, 1.0f, zb, 1.0f};
        __builtin_nontemporal_store(o, &out4[i]);
    }
}

extern "C" void kernel_launch(void* const* d_in, const int* in_sizes, int n_in,
                              void* d_out, int out_size, void* d_ws, size_t ws_size,
                              hipStream_t stream) {
    const float* x = (const float*)d_in[0];
    float* out = (float*)d_out;
    int n = in_sizes[0];     // B = 8388608
    int n2 = n / 2;          // 4194304 float2 elements

    int block = 256;
    int grid = 2048;         // grid-stride: 8 iterations/thread

    qp_kernel<<<grid, block, 0, stream>>>((const f2v*)x, (f4v*)out, n2);
}